// Round 1
// baseline (482.181 us; speedup 1.0000x reference)
//
#include <hip/hip_runtime.h>
#include <hip/hip_bf16.h>

#define D 128
#define BM 16

// Kernel 1: dual GEMM.
//   h   = x @ W_l                      (into workspace)
//   out = x @ W_r + bias_l + bias_r    (into d_out; scatter adds on top)
// Block = 256 threads. Threads 0..127 own h columns, 128..255 own out columns.
// x tile (16 rows x 128) staged in LDS; xs reads are wave-uniform (broadcast,
// conflict-free); W reads are coalesced 512B lines, L2-hot after first blocks.
__global__ __launch_bounds__(256) void gemm_dual(
    const float* __restrict__ x,
    const float* __restrict__ Wl, const float* __restrict__ Wr,
    const float* __restrict__ bl, const float* __restrict__ br,
    float* __restrict__ h, float* __restrict__ out, int n_nodes) {
  __shared__ float xs[BM][D];
  const int t = threadIdx.x;
  const int block_row = blockIdx.x * BM;

  // Stage x tile: 16*128 = 2048 floats = 512 float4; 256 threads -> 2 each.
  const float4* xsrc = (const float4*)(x + (size_t)block_row * D);
  float4* xdst = (float4*)(&xs[0][0]);
  xdst[t] = xsrc[t];
  xdst[t + 256] = xsrc[t + 256];
  __syncthreads();

  const int col = t & 127;
  const float* __restrict__ W = (t < 128) ? Wl : Wr;

  float acc[BM];
#pragma unroll
  for (int r = 0; r < BM; ++r) acc[r] = 0.f;

  for (int k = 0; k < D; k += 4) {
    const float w0 = W[(k + 0) * D + col];
    const float w1 = W[(k + 1) * D + col];
    const float w2 = W[(k + 2) * D + col];
    const float w3 = W[(k + 3) * D + col];
#pragma unroll
    for (int r = 0; r < BM; ++r) {
      const float4 xv = *(const float4*)&xs[r][k];
      acc[r] = fmaf(xv.x, w0, acc[r]);
      acc[r] = fmaf(xv.y, w1, acc[r]);
      acc[r] = fmaf(xv.z, w2, acc[r]);
      acc[r] = fmaf(xv.w, w3, acc[r]);
    }
  }

  if (t < 128) {
#pragma unroll
    for (int r = 0; r < BM; ++r)
      h[(size_t)(block_row + r) * D + col] = acc[r];
  } else {
    const float b = bl[col] + br[col];
#pragma unroll
    for (int r = 0; r < BM; ++r)
      out[(size_t)(block_row + r) * D + col] = acc[r] + b;
  }
}

// Kernel 2: edge scatter. out[dst] += w_e * h[src].
// 2 edges per 256-thread block; each wave has a uniform edge index, so
// src/dst/weight become scalar loads and the 128 feature lanes do coalesced
// 256B-per-wave gathers + same-cacheline atomics.
__global__ __launch_bounds__(256) void edge_scatter(
    const float* __restrict__ h,
    const int* __restrict__ esrc, const int* __restrict__ edst,
    const float* __restrict__ ew, float* __restrict__ out, int n_edges) {
  const int e = blockIdx.x * 2 + (threadIdx.x >> 7);
  if (e >= n_edges) return;
  const int f = threadIdx.x & 127;
  const int s = esrc[e];
  const int d = edst[e];
  const float w = ew[e];
  atomicAdd(&out[(size_t)d * D + f], w * h[(size_t)s * D + f]);
}

extern "C" void kernel_launch(void* const* d_in, const int* in_sizes, int n_in,
                              void* d_out, int out_size, void* d_ws, size_t ws_size,
                              hipStream_t stream) {
  const float* x   = (const float*)d_in[0];
  const int* esrc  = (const int*)d_in[1];
  const int* edst  = (const int*)d_in[2];
  const float* ew  = (const float*)d_in[3];
  const float* Wl  = (const float*)d_in[4];
  const float* bl  = (const float*)d_in[5];
  const float* Wr  = (const float*)d_in[6];
  const float* br  = (const float*)d_in[7];
  float* out = (float*)d_out;

  const int n_nodes = in_sizes[0] / D;   // 100000
  const int n_edges = in_sizes[1];       // 600000

  float* h = (float*)d_ws;               // n_nodes * D floats = 51.2 MB

  const int grid1 = (n_nodes + BM - 1) / BM;  // 6250 (exact)
  gemm_dual<<<grid1, 256, 0, stream>>>(x, Wl, Wr, bl, br, h, out, n_nodes);

  const int grid2 = (n_edges + 1) / 2;        // 300000
  edge_scatter<<<grid2, 256, 0, stream>>>(h, esrc, edst, ew, out, n_edges);
}

// Round 2
// 342.749 us; speedup vs baseline: 1.4068x; 1.4068x over previous
//
#include <hip/hip_runtime.h>
#include <hip/hip_bf16.h>

#define D 128
#define BM 16
#define SCAN_BLK 256
#define SCAN_VPT 4
#define SCAN_TILE (SCAN_BLK * SCAN_VPT)   // 1024 elements per scan block

// ---------------------------------------------------------------------------
// Kernel 1: dual GEMM (unchanged structure from R1; h now stored as bf16).
//   h   = bf16(x @ W_l)                  (into workspace)
//   out = x @ W_r + bias_l + bias_r      (into d_out; aggregation adds on top)
// ---------------------------------------------------------------------------
__global__ __launch_bounds__(256) void gemm_dual(
    const float* __restrict__ x,
    const float* __restrict__ Wl, const float* __restrict__ Wr,
    const float* __restrict__ bl, const float* __restrict__ br,
    __hip_bfloat16* __restrict__ h, float* __restrict__ out, int n_nodes) {
  __shared__ float xs[BM][D];
  const int t = threadIdx.x;
  const int block_row = blockIdx.x * BM;

  const float4* xsrc = (const float4*)(x + (size_t)block_row * D);
  float4* xdst = (float4*)(&xs[0][0]);
  xdst[t] = xsrc[t];
  xdst[t + 256] = xsrc[t + 256];
  __syncthreads();

  const int col = t & 127;
  const float* __restrict__ W = (t < 128) ? Wl : Wr;

  float acc[BM];
#pragma unroll
  for (int r = 0; r < BM; ++r) acc[r] = 0.f;

  for (int k = 0; k < D; k += 4) {
    const float w0 = W[(k + 0) * D + col];
    const float w1 = W[(k + 1) * D + col];
    const float w2 = W[(k + 2) * D + col];
    const float w3 = W[(k + 3) * D + col];
#pragma unroll
    for (int r = 0; r < BM; ++r) {
      const float4 xv = *(const float4*)&xs[r][k];
      acc[r] = fmaf(xv.x, w0, acc[r]);
      acc[r] = fmaf(xv.y, w1, acc[r]);
      acc[r] = fmaf(xv.z, w2, acc[r]);
      acc[r] = fmaf(xv.w, w3, acc[r]);
    }
  }

  if (t < 128) {
#pragma unroll
    for (int r = 0; r < BM; ++r)
      h[(size_t)(block_row + r) * D + col] = __float2bfloat16(acc[r]);
  } else {
    const float b = bl[col] + br[col];
#pragma unroll
    for (int r = 0; r < BM; ++r)
      out[(size_t)(block_row + r) * D + col] = acc[r] + b;
  }
}

// ---------------------------------------------------------------------------
// CSR build: histogram -> exclusive scan (3 kernels) -> scatter pairs
// ---------------------------------------------------------------------------
__global__ __launch_bounds__(256) void hist_kernel(
    const int* __restrict__ edst, int* __restrict__ deg, int n_edges) {
  const int e = blockIdx.x * 256 + threadIdx.x;
  if (e < n_edges) atomicAdd(&deg[edst[e]], 1);
}

// Block-level exclusive scan of deg -> offsets (partial, within-block), plus
// per-block totals into partials[].
__global__ __launch_bounds__(SCAN_BLK) void scan1_kernel(
    const int* __restrict__ deg, int* __restrict__ offsets,
    int* __restrict__ partials, int n) {
  __shared__ int sdata[SCAN_BLK];
  const int t = threadIdx.x;
  const int base = blockIdx.x * SCAN_TILE + t * SCAN_VPT;

  int v[SCAN_VPT];
  int s = 0;
#pragma unroll
  for (int j = 0; j < SCAN_VPT; ++j) {
    v[j] = (base + j < n) ? deg[base + j] : 0;
    s += v[j];
  }
  sdata[t] = s;
  __syncthreads();
  // Hillis-Steele inclusive scan over thread sums
  for (int off = 1; off < SCAN_BLK; off <<= 1) {
    int xv = (t >= off) ? sdata[t - off] : 0;
    __syncthreads();
    sdata[t] += xv;
    __syncthreads();
  }
  int excl = sdata[t] - s;              // exclusive prefix for this thread
  if (t == SCAN_BLK - 1) partials[blockIdx.x] = sdata[t];  // block total
  int run = excl;
#pragma unroll
  for (int j = 0; j < SCAN_VPT; ++j) {
    if (base + j < n) offsets[base + j] = run;
    run += v[j];
  }
}

__global__ void scan2_kernel(int* __restrict__ partials, int nparts) {
  if (threadIdx.x == 0 && blockIdx.x == 0) {
    int run = 0;
    for (int i = 0; i < nparts; ++i) {
      int xv = partials[i];
      partials[i] = run;
      run += xv;
    }
  }
}

// Add block bases; also materialize the pos[] cursor copy and offsets[n]=E.
__global__ __launch_bounds__(SCAN_BLK) void scan3_kernel(
    int* __restrict__ offsets, int* __restrict__ pos,
    const int* __restrict__ partials, int n, int n_edges) {
  const int base = blockIdx.x * SCAN_TILE + threadIdx.x * SCAN_VPT;
  const int add = partials[blockIdx.x];
#pragma unroll
  for (int j = 0; j < SCAN_VPT; ++j) {
    const int i = base + j;
    if (i < n) {
      const int o = offsets[i] + add;
      offsets[i] = o;
      pos[i] = o;
    }
  }
  if (blockIdx.x == 0 && threadIdx.x == 0) offsets[n] = n_edges;
}

// Scatter edges into dst-sorted slots: pairs[slot] = {src, bits(weight)}.
__global__ __launch_bounds__(256) void scatter_kernel(
    const int* __restrict__ esrc, const int* __restrict__ edst,
    const float* __restrict__ ew, int* __restrict__ pos,
    int2* __restrict__ pairs, int n_edges) {
  const int e = blockIdx.x * 256 + threadIdx.x;
  if (e >= n_edges) return;
  const int d = edst[e];
  const int slot = atomicAdd(&pos[d], 1);
  pairs[slot] = make_int2(esrc[e], __float_as_int(ew[e]));
}

// ---------------------------------------------------------------------------
// Aggregation: one wave per node. out[node] += sum_e w_e * h[src_e].
// No atomics; h gathered as bf16x2 (256B per edge per wave, contiguous).
// ---------------------------------------------------------------------------
__global__ __launch_bounds__(64) void aggregate_kernel(
    const __hip_bfloat16* __restrict__ h, const int* __restrict__ offsets,
    const int2* __restrict__ pairs, float* __restrict__ out, int n_nodes) {
  const int node = blockIdx.x;
  const int t = threadIdx.x;          // 0..63, owns features 2t, 2t+1
  const int begin = offsets[node];
  const int end = offsets[node + 1];

  float2 acc = *(const float2*)&out[(size_t)node * D + 2 * t];
  const __hip_bfloat162* h2 = (const __hip_bfloat162*)h;

  for (int i = begin; i < end; ++i) {
    const int2 p = pairs[i];
    const float w = __int_as_float(p.y);
    const __hip_bfloat162 hv = h2[(size_t)p.x * (D / 2) + t];
    acc.x = fmaf(w, __bfloat162float(hv.x), acc.x);
    acc.y = fmaf(w, __bfloat162float(hv.y), acc.y);
  }
  *(float2*)&out[(size_t)node * D + 2 * t] = acc;
}

// ---------------------------------------------------------------------------
extern "C" void kernel_launch(void* const* d_in, const int* in_sizes, int n_in,
                              void* d_out, int out_size, void* d_ws, size_t ws_size,
                              hipStream_t stream) {
  const float* x   = (const float*)d_in[0];
  const int* esrc  = (const int*)d_in[1];
  const int* edst  = (const int*)d_in[2];
  const float* ew  = (const float*)d_in[3];
  const float* Wl  = (const float*)d_in[4];
  const float* bl  = (const float*)d_in[5];
  const float* Wr  = (const float*)d_in[6];
  const float* br  = (const float*)d_in[7];
  float* out = (float*)d_out;

  const int n_nodes = in_sizes[0] / D;   // 100000
  const int n_edges = in_sizes[1];       // 600000

  // Workspace layout (16B aligned sections):
  char* ws = (char*)d_ws;
  __hip_bfloat16* h = (__hip_bfloat16*)ws;              // n_nodes*D*2 B = 25.6 MB
  size_t off = (size_t)n_nodes * D * sizeof(__hip_bfloat16);
  off = (off + 15) & ~15ull;
  int* offsets = (int*)(ws + off);                      // (n_nodes+1) ints
  off += (size_t)(n_nodes + 1) * sizeof(int);
  off = (off + 15) & ~15ull;
  int* pos = (int*)(ws + off);                          // n_nodes ints (deg, then cursors)
  off += (size_t)n_nodes * sizeof(int);
  off = (off + 15) & ~15ull;
  int* partials = (int*)(ws + off);                     // scan partials
  off += 1024 * sizeof(int);
  off = (off + 15) & ~15ull;
  int2* pairs = (int2*)(ws + off);                      // n_edges int2 = 4.8 MB

  const int grid1 = (n_nodes + BM - 1) / BM;
  gemm_dual<<<grid1, 256, 0, stream>>>(x, Wl, Wr, bl, br, h, out, n_nodes);

  // CSR build (pos doubles as the degree histogram, zeroed each launch)
  hipMemsetAsync(pos, 0, (size_t)n_nodes * sizeof(int), stream);
  hist_kernel<<<(n_edges + 255) / 256, 256, 0, stream>>>(edst, pos, n_edges);

  const int nparts = (n_nodes + SCAN_TILE - 1) / SCAN_TILE;   // 98
  scan1_kernel<<<nparts, SCAN_BLK, 0, stream>>>(pos, offsets, partials, n_nodes);
  scan2_kernel<<<1, 64, 0, stream>>>(partials, nparts);
  scan3_kernel<<<nparts, SCAN_BLK, 0, stream>>>(offsets, pos, partials, n_nodes, n_edges);

  scatter_kernel<<<(n_edges + 255) / 256, 256, 0, stream>>>(esrc, edst, ew, pos, pairs, n_edges);

  aggregate_kernel<<<n_nodes, 64, 0, stream>>>(h, offsets, pairs, out, n_nodes);
}

// Round 3
// 250.963 us; speedup vs baseline: 1.9213x; 1.3657x over previous
//
#include <hip/hip_runtime.h>
#include <hip/hip_bf16.h>

#define D 128
#define SCAN_BLK 256
#define SCAN_VPT 4
#define SCAN_TILE (SCAN_BLK * SCAN_VPT)   // 1024 elements per scan block

typedef __attribute__((ext_vector_type(8))) short short8;   // 8 bf16 = 4 VGPR
typedef __attribute__((ext_vector_type(4))) float f32x4;    // MFMA C/D frag

// ---------------------------------------------------------------------------
// prep_w: WTl/WTr = bf16 transpose of Wl/Wr ([n][k] layout, 16B-loadable
// B-fragments); bsum = bl + br. Tiny (32K elements).
// ---------------------------------------------------------------------------
__global__ __launch_bounds__(256) void prep_w(
    const float* __restrict__ Wl, const float* __restrict__ Wr,
    const float* __restrict__ bl, const float* __restrict__ br,
    __hip_bfloat16* __restrict__ WTl, __hip_bfloat16* __restrict__ WTr,
    float* __restrict__ bsum) {
  const int tid = blockIdx.x * 256 + threadIdx.x;  // grid 128 -> 0..32767
  const int n = (tid >> 7) & 127;
  const int k = tid & 127;
  if (tid < 16384) {
    WTl[n * D + k] = __float2bfloat16(Wl[k * D + n]);
  } else {
    WTr[n * D + k] = __float2bfloat16(Wr[k * D + n]);
  }
  if (tid < 128) bsum[tid] = bl[tid] + br[tid];
}

// ---------------------------------------------------------------------------
// gemm_mfma: per 16-row tile compute
//   h[rows]   = bf16(x @ Wl)          (waves 0,1)
//   out[rows] = x @ Wr + bsum         (waves 2,3)
// B-fragments (WT) preloaded into registers once per block, reused across a
// grid-stride loop over row tiles. x tile staged fp32->bf16 into padded LDS.
// MFMA 16x16x32 bf16; layouts per learn_hip m89 (A: [m=lane&15][k=q*8+j],
// D: col=lane&15, row=q*4+reg).
// ---------------------------------------------------------------------------
__global__ __launch_bounds__(256) void gemm_mfma(
    const float* __restrict__ x,
    const __hip_bfloat16* __restrict__ WTl,
    const __hip_bfloat16* __restrict__ WTr,
    const float* __restrict__ bsum,
    __hip_bfloat16* __restrict__ h,
    float* __restrict__ out,
    int n_rowtiles) {
  // +8 bf16 pad -> row stride 272B: afrag b128 reads spread 8 lanes/bank-group
  __shared__ __hip_bfloat16 xs[16][136];
  const int t = threadIdx.x;
  const int wave = t >> 6;
  const int lane = t & 63;
  const int m = lane & 15;
  const int q = lane >> 4;

  // B fragment preload: wave 0/1 -> Wl cols 0-63/64-127; wave 2/3 -> Wr same.
  const __hip_bfloat16* __restrict__ WT = (wave < 2) ? WTl : WTr;
  const int ctbase = (wave & 1) * 4;
  short8 bfrag[4][4];
#pragma unroll
  for (int ct = 0; ct < 4; ++ct) {
    const int n0 = (ctbase + ct) * 16;
#pragma unroll
    for (int ks = 0; ks < 4; ++ks)
      bfrag[ct][ks] = *(const short8*)&WT[(n0 + m) * D + ks * 32 + q * 8];
  }

  const int srow = t >> 4;          // staging: row 0..15
  const int scol = (t & 15) * 8;    // col group of 8 floats

  for (int rt = blockIdx.x; rt < n_rowtiles; rt += gridDim.x) {
    const int rowbase = rt * 16;
    // stage x tile, fp32 -> bf16 (16B-aligned LDS writes: 272B row stride)
    {
      const float4* src = (const float4*)&x[(size_t)(rowbase + srow) * D + scol];
      const float4 v0 = src[0], v1 = src[1];
      __hip_bfloat16* dst = &xs[srow][scol];
      dst[0] = __float2bfloat16(v0.x); dst[1] = __float2bfloat16(v0.y);
      dst[2] = __float2bfloat16(v0.z); dst[3] = __float2bfloat16(v0.w);
      dst[4] = __float2bfloat16(v1.x); dst[5] = __float2bfloat16(v1.y);
      dst[6] = __float2bfloat16(v1.z); dst[7] = __float2bfloat16(v1.w);
    }
    __syncthreads();

    f32x4 acc[4];
#pragma unroll
    for (int ct = 0; ct < 4; ++ct)
#pragma unroll
      for (int r = 0; r < 4; ++r) acc[ct][r] = 0.f;

#pragma unroll
    for (int ks = 0; ks < 4; ++ks) {
      const short8 afrag = *(const short8*)&xs[m][ks * 32 + q * 8];
#pragma unroll
      for (int ct = 0; ct < 4; ++ct)
        acc[ct] = __builtin_amdgcn_mfma_f32_16x16x32_bf16(afrag, bfrag[ct][ks], acc[ct], 0, 0, 0);
    }

    if (wave < 2) {
#pragma unroll
      for (int ct = 0; ct < 4; ++ct) {
        const int n = (ctbase + ct) * 16 + m;
#pragma unroll
        for (int r = 0; r < 4; ++r)
          h[(size_t)(rowbase + q * 4 + r) * D + n] = __float2bfloat16(acc[ct][r]);
      }
    } else {
#pragma unroll
      for (int ct = 0; ct < 4; ++ct) {
        const int n = (ctbase + ct) * 16 + m;
        const float b = bsum[n];
#pragma unroll
        for (int r = 0; r < 4; ++r)
          out[(size_t)(rowbase + q * 4 + r) * D + n] = acc[ct][r] + b;
      }
    }
    __syncthreads();  // protect xs before next tile's staging
  }
}

// ---------------------------------------------------------------------------
// CSR build: histogram -> exclusive scan -> scatter pairs
// ---------------------------------------------------------------------------
__global__ __launch_bounds__(256) void hist_kernel(
    const int* __restrict__ edst, int* __restrict__ deg, int n_edges) {
  const int e = blockIdx.x * 256 + threadIdx.x;
  if (e < n_edges) atomicAdd(&deg[edst[e]], 1);
}

__global__ __launch_bounds__(SCAN_BLK) void scan1_kernel(
    const int* __restrict__ deg, int* __restrict__ offsets,
    int* __restrict__ partials, int n) {
  __shared__ int sdata[SCAN_BLK];
  const int t = threadIdx.x;
  const int base = blockIdx.x * SCAN_TILE + t * SCAN_VPT;

  int v[SCAN_VPT];
  int s = 0;
#pragma unroll
  for (int j = 0; j < SCAN_VPT; ++j) {
    v[j] = (base + j < n) ? deg[base + j] : 0;
    s += v[j];
  }
  sdata[t] = s;
  __syncthreads();
  for (int off = 1; off < SCAN_BLK; off <<= 1) {
    int xv = (t >= off) ? sdata[t - off] : 0;
    __syncthreads();
    sdata[t] += xv;
    __syncthreads();
  }
  int excl = sdata[t] - s;
  if (t == SCAN_BLK - 1) partials[blockIdx.x] = sdata[t];
  int run = excl;
#pragma unroll
  for (int j = 0; j < SCAN_VPT; ++j) {
    if (base + j < n) offsets[base + j] = run;
    run += v[j];
  }
}

// Parallel single-block exclusive scan over block partials (nparts <= 128).
__global__ __launch_bounds__(128) void scan2_kernel(int* __restrict__ partials, int nparts) {
  __shared__ int sd[128];
  const int t = threadIdx.x;
  const int v = (t < nparts) ? partials[t] : 0;
  sd[t] = v;
  __syncthreads();
  for (int off = 1; off < 128; off <<= 1) {
    int xv = (t >= off) ? sd[t - off] : 0;
    __syncthreads();
    sd[t] += xv;
    __syncthreads();
  }
  if (t < nparts) partials[t] = sd[t] - v;  // exclusive
}

__global__ __launch_bounds__(SCAN_BLK) void scan3_kernel(
    int* __restrict__ offsets, int* __restrict__ pos,
    const int* __restrict__ partials, int n, int n_edges) {
  const int base = blockIdx.x * SCAN_TILE + threadIdx.x * SCAN_VPT;
  const int add = partials[blockIdx.x];
#pragma unroll
  for (int j = 0; j < SCAN_VPT; ++j) {
    const int i = base + j;
    if (i < n) {
      const int o = offsets[i] + add;
      offsets[i] = o;
      pos[i] = o;
    }
  }
  if (blockIdx.x == 0 && threadIdx.x == 0) offsets[n] = n_edges;
}

__global__ __launch_bounds__(256) void scatter_kernel(
    const int* __restrict__ esrc, const int* __restrict__ edst,
    const float* __restrict__ ew, int* __restrict__ pos,
    int2* __restrict__ pairs, int n_edges) {
  const int e = blockIdx.x * 256 + threadIdx.x;
  if (e >= n_edges) return;
  const int d = edst[e];
  const int slot = atomicAdd(&pos[d], 1);
  pairs[slot] = make_int2(esrc[e], __float_as_int(ew[e]));
}

// ---------------------------------------------------------------------------
// aggregate: one wave per node, 4 nodes per block. 4-edge chunks keep 4
// independent h-gathers in flight (vs 1 dependent chain) to hide L2/L3
// latency. out[node] += sum_e w_e * h[src_e].
// ---------------------------------------------------------------------------
__global__ __launch_bounds__(256) void aggregate_kernel(
    const __hip_bfloat16* __restrict__ h, const int* __restrict__ offsets,
    const int2* __restrict__ pairs, float* __restrict__ out, int n_nodes) {
  const int node = blockIdx.x * 4 + (threadIdx.x >> 6);
  if (node >= n_nodes) return;
  const int t = threadIdx.x & 63;
  const int begin = offsets[node];
  const int end = offsets[node + 1];
  const __hip_bfloat162* __restrict__ h2 = (const __hip_bfloat162*)h;

  float2 acc = *(const float2*)&out[(size_t)node * D + 2 * t];

  int i = begin;
  for (; i + 4 <= end; i += 4) {
    const int2 p0 = pairs[i + 0];
    const int2 p1 = pairs[i + 1];
    const int2 p2 = pairs[i + 2];
    const int2 p3 = pairs[i + 3];
    const __hip_bfloat162 a0 = h2[(size_t)p0.x * (D / 2) + t];
    const __hip_bfloat162 a1 = h2[(size_t)p1.x * (D / 2) + t];
    const __hip_bfloat162 a2 = h2[(size_t)p2.x * (D / 2) + t];
    const __hip_bfloat162 a3 = h2[(size_t)p3.x * (D / 2) + t];
    const float w0 = __int_as_float(p0.y), w1 = __int_as_float(p1.y);
    const float w2 = __int_as_float(p2.y), w3 = __int_as_float(p3.y);
    acc.x = fmaf(w0, __bfloat162float(a0.x), acc.x);
    acc.y = fmaf(w0, __bfloat162float(a0.y), acc.y);
    acc.x = fmaf(w1, __bfloat162float(a1.x), acc.x);
    acc.y = fmaf(w1, __bfloat162float(a1.y), acc.y);
    acc.x = fmaf(w2, __bfloat162float(a2.x), acc.x);
    acc.y = fmaf(w2, __bfloat162float(a2.y), acc.y);
    acc.x = fmaf(w3, __bfloat162float(a3.x), acc.x);
    acc.y = fmaf(w3, __bfloat162float(a3.y), acc.y);
  }
  for (; i < end; ++i) {
    const int2 p = pairs[i];
    const __hip_bfloat162 a = h2[(size_t)p.x * (D / 2) + t];
    const float w = __int_as_float(p.y);
    acc.x = fmaf(w, __bfloat162float(a.x), acc.x);
    acc.y = fmaf(w, __bfloat162float(a.y), acc.y);
  }
  *(float2*)&out[(size_t)node * D + 2 * t] = acc;
}

// ---------------------------------------------------------------------------
extern "C" void kernel_launch(void* const* d_in, const int* in_sizes, int n_in,
                              void* d_out, int out_size, void* d_ws, size_t ws_size,
                              hipStream_t stream) {
  const float* x   = (const float*)d_in[0];
  const int* esrc  = (const int*)d_in[1];
  const int* edst  = (const int*)d_in[2];
  const float* ew  = (const float*)d_in[3];
  const float* Wl  = (const float*)d_in[4];
  const float* bl  = (const float*)d_in[5];
  const float* Wr  = (const float*)d_in[6];
  const float* br  = (const float*)d_in[7];
  float* out = (float*)d_out;

  const int n_nodes = in_sizes[0] / D;   // 100000
  const int n_edges = in_sizes[1];       // 600000

  // Workspace layout (16B aligned sections)
  char* ws = (char*)d_ws;
  size_t off = 0;
  __hip_bfloat16* h = (__hip_bfloat16*)(ws + off);      // 25.6 MB
  off += (size_t)n_nodes * D * sizeof(__hip_bfloat16);
  off = (off + 15) & ~15ull;
  int* offsets = (int*)(ws + off);
  off += (size_t)(n_nodes + 1) * sizeof(int);
  off = (off + 15) & ~15ull;
  int* pos = (int*)(ws + off);                          // degree, then cursors
  off += (size_t)n_nodes * sizeof(int);
  off = (off + 15) & ~15ull;
  int* partials = (int*)(ws + off);
  off += 1024 * sizeof(int);
  off = (off + 15) & ~15ull;
  int2* pairs = (int2*)(ws + off);                      // 4.8 MB
  off += (size_t)n_edges * sizeof(int2);
  off = (off + 15) & ~15ull;
  __hip_bfloat16* WTl = (__hip_bfloat16*)(ws + off);
  off += (size_t)D * D * sizeof(__hip_bfloat16);
  __hip_bfloat16* WTr = (__hip_bfloat16*)(ws + off);
  off += (size_t)D * D * sizeof(__hip_bfloat16);
  float* bsum = (float*)(ws + off);
  off += D * sizeof(float);

  // Weight prep, then MFMA dual-GEMM
  prep_w<<<128, 256, 0, stream>>>(Wl, Wr, bl, br, WTl, WTr, bsum);
  const int n_rowtiles = (n_nodes + 15) / 16;           // 6250 (exact)
  const int gemm_grid = n_rowtiles < 2048 ? n_rowtiles : 2048;
  gemm_mfma<<<gemm_grid, 256, 0, stream>>>(x, WTl, WTr, bsum, h, out, n_rowtiles);

  // CSR build (pos doubles as the degree histogram)
  hipMemsetAsync(pos, 0, (size_t)n_nodes * sizeof(int), stream);
  hist_kernel<<<(n_edges + 255) / 256, 256, 0, stream>>>(edst, pos, n_edges);
  const int nparts = (n_nodes + SCAN_TILE - 1) / SCAN_TILE;   // 98 (<=128)
  scan1_kernel<<<nparts, SCAN_BLK, 0, stream>>>(pos, offsets, partials, n_nodes);
  scan2_kernel<<<1, 128, 0, stream>>>(partials, nparts);
  scan3_kernel<<<nparts, SCAN_BLK, 0, stream>>>(offsets, pos, partials, n_nodes, n_edges);
  scatter_kernel<<<(n_edges + 255) / 256, 256, 0, stream>>>(esrc, edst, ew, pos, pairs, n_edges);

  // Edge aggregation (no atomics)
  aggregate_kernel<<<(n_nodes + 3) / 4, 256, 0, stream>>>(h, offsets, pairs, out, n_nodes);
}

// Round 4
// 236.813 us; speedup vs baseline: 2.0361x; 1.0598x over previous
//
#include <hip/hip_runtime.h>
#include <hip/hip_bf16.h>

#define D 128
#define SCAN_BLK 256
#define SCAN_VPT 4
#define SCAN_TILE (SCAN_BLK * SCAN_VPT)   // 1024 elements per scan block

typedef __attribute__((ext_vector_type(8))) short short8;   // 8 bf16 = 4 VGPR
typedef __attribute__((ext_vector_type(4))) float f32x4;    // MFMA C/D frag

// ---------------------------------------------------------------------------
// prep_w: WTl/WTr = bf16 transpose of Wl/Wr ([n][k] layout, 16B B-fragments);
// bsum = bl + br.
// ---------------------------------------------------------------------------
__global__ __launch_bounds__(256) void prep_w(
    const float* __restrict__ Wl, const float* __restrict__ Wr,
    const float* __restrict__ bl, const float* __restrict__ br,
    __hip_bfloat16* __restrict__ WTl, __hip_bfloat16* __restrict__ WTr,
    float* __restrict__ bsum) {
  const int tid = blockIdx.x * 256 + threadIdx.x;  // grid 128 -> 0..32767
  const int n = (tid >> 7) & 127;
  const int k = tid & 127;
  if (tid < 16384) {
    WTl[n * D + k] = __float2bfloat16(Wl[k * D + n]);
  } else {
    WTr[n * D + k] = __float2bfloat16(Wr[k * D + n]);
  }
  if (tid < 128) bsum[tid] = bl[tid] + br[tid];
}

// ---------------------------------------------------------------------------
// gemm_h: h = bf16(x @ Wl). Also absorbs the degree histogram as a
// grid-stride prologue (atomics overlap with other waves' MFMA).
// Per 16-row tile: 4 waves x 2 col-tiles of 16. B-frags preloaded once.
// ---------------------------------------------------------------------------
__global__ __launch_bounds__(256) void gemm_h(
    const float* __restrict__ x, const __hip_bfloat16* __restrict__ WTl,
    __hip_bfloat16* __restrict__ h,
    const int* __restrict__ edst, int* __restrict__ deg, int n_edges,
    int n_rowtiles) {
  // histogram prologue
  const int gsz = gridDim.x * 256;
  for (int e = blockIdx.x * 256 + threadIdx.x; e < n_edges; e += gsz)
    atomicAdd(&deg[edst[e]], 1);

  __shared__ __hip_bfloat16 xs[16][136];   // +8 pad
  const int t = threadIdx.x;
  const int wave = t >> 6;
  const int lane = t & 63;
  const int m = lane & 15;
  const int q = lane >> 4;

  short8 bfrag[2][4];
#pragma unroll
  for (int c = 0; c < 2; ++c) {
    const int n0 = wave * 32 + c * 16;
#pragma unroll
    for (int ks = 0; ks < 4; ++ks)
      bfrag[c][ks] = *(const short8*)&WTl[(n0 + m) * D + ks * 32 + q * 8];
  }

  const int srow = t >> 4;
  const int scol = (t & 15) * 8;

  for (int rt = blockIdx.x; rt < n_rowtiles; rt += gridDim.x) {
    const int rowbase = rt * 16;
    {
      const float4* src = (const float4*)&x[(size_t)(rowbase + srow) * D + scol];
      const float4 v0 = src[0], v1 = src[1];
      __hip_bfloat16* dst = &xs[srow][scol];
      dst[0] = __float2bfloat16(v0.x); dst[1] = __float2bfloat16(v0.y);
      dst[2] = __float2bfloat16(v0.z); dst[3] = __float2bfloat16(v0.w);
      dst[4] = __float2bfloat16(v1.x); dst[5] = __float2bfloat16(v1.y);
      dst[6] = __float2bfloat16(v1.z); dst[7] = __float2bfloat16(v1.w);
    }
    __syncthreads();

    f32x4 acc[2];
#pragma unroll
    for (int c = 0; c < 2; ++c)
#pragma unroll
      for (int r = 0; r < 4; ++r) acc[c][r] = 0.f;

#pragma unroll
    for (int ks = 0; ks < 4; ++ks) {
      const short8 afrag = *(const short8*)&xs[m][ks * 32 + q * 8];
#pragma unroll
      for (int c = 0; c < 2; ++c)
        acc[c] = __builtin_amdgcn_mfma_f32_16x16x32_bf16(afrag, bfrag[c][ks], acc[c], 0, 0, 0);
    }

#pragma unroll
    for (int c = 0; c < 2; ++c) {
      const int n = wave * 32 + c * 16 + m;
#pragma unroll
      for (int r = 0; r < 4; ++r)
        h[(size_t)(rowbase + q * 4 + r) * D + n] = __float2bfloat16(acc[c][r]);
    }
    __syncthreads();
  }
}

// ---------------------------------------------------------------------------
// scan1: block-level exclusive scan of deg -> offsets + per-block totals.
// ---------------------------------------------------------------------------
__global__ __launch_bounds__(SCAN_BLK) void scan1_kernel(
    const int* __restrict__ deg, int* __restrict__ offsets,
    int* __restrict__ partials, int n) {
  __shared__ int sdata[SCAN_BLK];
  const int t = threadIdx.x;
  const int base = blockIdx.x * SCAN_TILE + t * SCAN_VPT;

  int v[SCAN_VPT];
  int s = 0;
#pragma unroll
  for (int j = 0; j < SCAN_VPT; ++j) {
    v[j] = (base + j < n) ? deg[base + j] : 0;
    s += v[j];
  }
  sdata[t] = s;
  __syncthreads();
  for (int off = 1; off < SCAN_BLK; off <<= 1) {
    int xv = (t >= off) ? sdata[t - off] : 0;
    __syncthreads();
    sdata[t] += xv;
    __syncthreads();
  }
  int excl = sdata[t] - s;
  if (t == SCAN_BLK - 1) partials[blockIdx.x] = sdata[t];
  int run = excl;
#pragma unroll
  for (int j = 0; j < SCAN_VPT; ++j) {
    if (base + j < n) offsets[base + j] = run;
    run += v[j];
  }
}

// ---------------------------------------------------------------------------
// scan3: adds block-prefix (computed inline by wave 0 — scan2 folded in),
// materializes pos[] cursors and offsets[n] = E.
// ---------------------------------------------------------------------------
__global__ __launch_bounds__(SCAN_BLK) void scan3_kernel(
    int* __restrict__ offsets, int* __restrict__ pos,
    const int* __restrict__ partials, int n, int n_edges) {
  __shared__ int s_add;
  const int t = threadIdx.x;
  if (t < 64) {
    int v = 0;
    for (int j = t; j < blockIdx.x; j += 64) v += partials[j];
#pragma unroll
    for (int off = 32; off > 0; off >>= 1) v += __shfl_down(v, off);
    if (t == 0) s_add = v;
  }
  __syncthreads();
  const int add = s_add;
  const int base = blockIdx.x * SCAN_TILE + t * SCAN_VPT;
#pragma unroll
  for (int j = 0; j < SCAN_VPT; ++j) {
    const int i = base + j;
    if (i < n) {
      const int o = offsets[i] + add;
      offsets[i] = o;
      pos[i] = o;
    }
  }
  if (blockIdx.x == 0 && t == 0) offsets[n] = n_edges;
}

// ---------------------------------------------------------------------------
// scatter: pairs[slot] = {src, bits(weight)} in dst-sorted order.
// ---------------------------------------------------------------------------
__global__ __launch_bounds__(256) void scatter_kernel(
    const int* __restrict__ esrc, const int* __restrict__ edst,
    const float* __restrict__ ew, int* __restrict__ pos,
    int2* __restrict__ pairs, int n_edges) {
  const int e = blockIdx.x * 256 + threadIdx.x;
  if (e >= n_edges) return;
  const int d = edst[e];
  const int slot = atomicAdd(&pos[d], 1);
  pairs[slot] = make_int2(esrc[e], __float_as_int(ew[e]));
}

// ---------------------------------------------------------------------------
// sage_out: fused root-GEMM + aggregation. Per 16-node tile:
//   phase 1: MFMA x @ Wr + bsum -> LDS tile ot[16][128]
//   phase 2: each wave aggregates 4 nodes' edges on top of ot, writes out ONCE
// Kills the gemm out-write + aggregate out-read (~100 MB HBM).
// ---------------------------------------------------------------------------
__global__ __launch_bounds__(256) void sage_out(
    const float* __restrict__ x, const __hip_bfloat16* __restrict__ WTr,
    const float* __restrict__ bsum, const __hip_bfloat16* __restrict__ h,
    const int* __restrict__ offsets, const int2* __restrict__ pairs,
    float* __restrict__ out) {
  __shared__ __hip_bfloat16 xs[16][136];
  __shared__ float ot[16][D];
  const int t = threadIdx.x;
  const int wave = t >> 6;
  const int lane = t & 63;
  const int m = lane & 15;
  const int q = lane >> 4;
  const int rowbase = blockIdx.x * 16;

  // B fragments: Wr cols wave*32 .. +31
  short8 bfrag[2][4];
#pragma unroll
  for (int c = 0; c < 2; ++c) {
    const int n0 = wave * 32 + c * 16;
#pragma unroll
    for (int ks = 0; ks < 4; ++ks)
      bfrag[c][ks] = *(const short8*)&WTr[(n0 + m) * D + ks * 32 + q * 8];
  }

  // stage x tile fp32 -> bf16
  {
    const int srow = t >> 4;
    const int scol = (t & 15) * 8;
    const float4* src = (const float4*)&x[(size_t)(rowbase + srow) * D + scol];
    const float4 v0 = src[0], v1 = src[1];
    __hip_bfloat16* dst = &xs[srow][scol];
    dst[0] = __float2bfloat16(v0.x); dst[1] = __float2bfloat16(v0.y);
    dst[2] = __float2bfloat16(v0.z); dst[3] = __float2bfloat16(v0.w);
    dst[4] = __float2bfloat16(v1.x); dst[5] = __float2bfloat16(v1.y);
    dst[6] = __float2bfloat16(v1.z); dst[7] = __float2bfloat16(v1.w);
  }
  __syncthreads();

  f32x4 acc[2];
#pragma unroll
  for (int c = 0; c < 2; ++c)
#pragma unroll
    for (int r = 0; r < 4; ++r) acc[c][r] = 0.f;

#pragma unroll
  for (int ks = 0; ks < 4; ++ks) {
    const short8 afrag = *(const short8*)&xs[m][ks * 32 + q * 8];
#pragma unroll
    for (int c = 0; c < 2; ++c)
      acc[c] = __builtin_amdgcn_mfma_f32_16x16x32_bf16(afrag, bfrag[c][ks], acc[c], 0, 0, 0);
  }

#pragma unroll
  for (int c = 0; c < 2; ++c) {
    const int n = wave * 32 + c * 16 + m;
    const float b = bsum[n];
#pragma unroll
    for (int r = 0; r < 4; ++r)
      ot[q * 4 + r][n] = acc[c][r] + b;
  }
  __syncthreads();

  // phase 2: wave handles nodes rowbase + wave*4 + 0..3
  const __hip_bfloat162* __restrict__ h2 = (const __hip_bfloat162*)h;
#pragma unroll
  for (int j = 0; j < 4; ++j) {
    const int ln = wave * 4 + j;
    const int node = rowbase + ln;
    const int begin = offsets[node];
    const int end = offsets[node + 1];

    float2 a = *(const float2*)&ot[ln][2 * lane];

    int i = begin;
    for (; i + 4 <= end; i += 4) {
      const int2 p0 = pairs[i + 0];
      const int2 p1 = pairs[i + 1];
      const int2 p2 = pairs[i + 2];
      const int2 p3 = pairs[i + 3];
      const __hip_bfloat162 a0 = h2[(size_t)p0.x * (D / 2) + lane];
      const __hip_bfloat162 a1 = h2[(size_t)p1.x * (D / 2) + lane];
      const __hip_bfloat162 a2 = h2[(size_t)p2.x * (D / 2) + lane];
      const __hip_bfloat162 a3 = h2[(size_t)p3.x * (D / 2) + lane];
      const float w0 = __int_as_float(p0.y), w1 = __int_as_float(p1.y);
      const float w2 = __int_as_float(p2.y), w3 = __int_as_float(p3.y);
      a.x = fmaf(w0, __bfloat162float(a0.x), a.x);
      a.y = fmaf(w0, __bfloat162float(a0.y), a.y);
      a.x = fmaf(w1, __bfloat162float(a1.x), a.x);
      a.y = fmaf(w1, __bfloat162float(a1.y), a.y);
      a.x = fmaf(w2, __bfloat162float(a2.x), a.x);
      a.y = fmaf(w2, __bfloat162float(a2.y), a.y);
      a.x = fmaf(w3, __bfloat162float(a3.x), a.x);
      a.y = fmaf(w3, __bfloat162float(a3.y), a.y);
    }
    for (; i < end; ++i) {
      const int2 p = pairs[i];
      const __hip_bfloat162 av = h2[(size_t)p.x * (D / 2) + lane];
      const float w = __int_as_float(p.y);
      a.x = fmaf(w, __bfloat162float(av.x), a.x);
      a.y = fmaf(w, __bfloat162float(av.y), a.y);
    }
    *(float2*)&out[(size_t)node * D + 2 * lane] = a;
  }
}

// ---------------------------------------------------------------------------
extern "C" void kernel_launch(void* const* d_in, const int* in_sizes, int n_in,
                              void* d_out, int out_size, void* d_ws, size_t ws_size,
                              hipStream_t stream) {
  const float* x   = (const float*)d_in[0];
  const int* esrc  = (const int*)d_in[1];
  const int* edst  = (const int*)d_in[2];
  const float* ew  = (const float*)d_in[3];
  const float* Wl  = (const float*)d_in[4];
  const float* bl  = (const float*)d_in[5];
  const float* Wr  = (const float*)d_in[6];
  const float* br  = (const float*)d_in[7];
  float* out = (float*)d_out;

  const int n_nodes = in_sizes[0] / D;   // 100000
  const int n_edges = in_sizes[1];       // 600000

  // Workspace layout (16B aligned sections)
  char* ws = (char*)d_ws;
  size_t off = 0;
  __hip_bfloat16* h = (__hip_bfloat16*)(ws + off);      // 25.6 MB
  off += (size_t)n_nodes * D * sizeof(__hip_bfloat16);
  off = (off + 15) & ~15ull;
  int* offsets = (int*)(ws + off);
  off += (size_t)(n_nodes + 1) * sizeof(int);
  off = (off + 15) & ~15ull;
  int* pos = (int*)(ws + off);                          // degree, then cursors
  off += (size_t)n_nodes * sizeof(int);
  off = (off + 15) & ~15ull;
  int* partials = (int*)(ws + off);
  off += 1024 * sizeof(int);
  off = (off + 15) & ~15ull;
  int2* pairs = (int2*)(ws + off);                      // 4.8 MB
  off += (size_t)n_edges * sizeof(int2);
  off = (off + 15) & ~15ull;
  __hip_bfloat16* WTl = (__hip_bfloat16*)(ws + off);
  off += (size_t)D * D * sizeof(__hip_bfloat16);
  __hip_bfloat16* WTr = (__hip_bfloat16*)(ws + off);
  off += (size_t)D * D * sizeof(__hip_bfloat16);
  float* bsum = (float*)(ws + off);
  off += D * sizeof(float);

  const int n_rowtiles = (n_nodes + 15) / 16;           // 6250 (exact)

  hipMemsetAsync(pos, 0, (size_t)n_nodes * sizeof(int), stream);
  prep_w<<<128, 256, 0, stream>>>(Wl, Wr, bl, br, WTl, WTr, bsum);

  const int gemm_grid = n_rowtiles < 2048 ? n_rowtiles : 2048;
  gemm_h<<<gemm_grid, 256, 0, stream>>>(x, WTl, h, edst, pos, n_edges, n_rowtiles);

  const int nparts = (n_nodes + SCAN_TILE - 1) / SCAN_TILE;   // 98
  scan1_kernel<<<nparts, SCAN_BLK, 0, stream>>>(pos, offsets, partials, n_nodes);
  scan3_kernel<<<nparts, SCAN_BLK, 0, stream>>>(offsets, pos, partials, n_nodes, n_edges);
  scatter_kernel<<<(n_edges + 255) / 256, 256, 0, stream>>>(esrc, edst, ew, pos, pairs, n_edges);

  sage_out<<<n_rowtiles, 256, 0, stream>>>(x, WTr, bsum, h, offsets, pairs, out);
}